// Round 8
// baseline (222.471 us; speedup 1.0000x reference)
//
#include <hip/hip_runtime.h>

#define HH 512
#define WW 512
#define TT 16
#define NF 14   // pred/target frames per video
#define NV 4    // videos
#define CRP 17
#define CW 478  // cropped width
#define TGT_SIZE ((size_t)NV * NF * CW * CW)   // 12,795,104
#define FRAME ((size_t)HH * WW)

#define WROWS 48
#define WCOLS 80
#define WSTR  85                 // ODD stride: 85 % 32 = 21 -> per-group row spread
                                 // covers all residues mod 8 (bank-conflict fix)
#define WBASE (2 * WSTR + 2)     // 2-row/2-col margin so all batched reads are in-bounds
#define WSIZE ((WROWS + 4) * WSTR)   // 52*85 = 4420 dwords = 17,680 B
#define TH    1e-3f              // hybrid fallback margin (bound on f32 tree err ~7e-5)

#define NMOTION (NV * NF * 16 * 8)           // 7168 motion CTAs
#define N4      ((int)(TGT_SIZE / 4))        // 3,198,776 float4s
#define SPAN    447                          // float4s copied per CTA (7168*447 >= N4)

// ---- 8-lane group sum entirely on the VALU ----
// Bitwise-identical to __shfl_xor(1)/(2)/(4):
//   quad_perm [1,0,3,2] == lane^1 ; quad_perm [2,3,0,1] == lane^2 ;
//   row_half_mirror == lane^4 once the value is quad-uniform.
// All patterns stay inside the 8-lane group, whose exec state is uniform,
// so masking done-groups never corrupts the reduce.
template <int CTRL>
__device__ __forceinline__ float dpp_add(float v) {
    int x = __builtin_amdgcn_update_dpp(0, __float_as_int(v), CTRL, 0xF, 0xF, true);
    return v + __int_as_float(x);
}
__device__ __forceinline__ float bf8_sum(float v) {
    v = dpp_add<0xB1>(v);    // quad_perm [1,0,3,2]
    v = dpp_add<0x4E>(v);    // quad_perm [2,3,0,1]
    v = dpp_add<0x141>(v);   // row_half_mirror
    return v;
}
__device__ __forceinline__ double bf8_sumd(double v) {   // rare exact path
    v += __shfl_xor(v, 1, 64);
    v += __shfl_xor(v, 2, 64);
    v += __shfl_xor(v, 4, 64);
    return v;
}

// f32 SAD of this lane's 8-pixel row vs 8 window scalars already in registers,
// then 3-stage group reduce. Term order/association identical to the original.
__device__ __forceinline__ float sad8(float w0, float w1, float w2, float w3,
                                      float w4, float w5, float w6, float w7,
                                      const float2* pr2) {
    float t0 = fabsf(pr2[0].x - w0) + fabsf(pr2[0].y - w1);
    float t1 = fabsf(pr2[1].x - w2) + fabsf(pr2[1].y - w3);
    float t2 = fabsf(pr2[2].x - w4) + fabsf(pr2[2].y - w5);
    float t3 = fabsf(pr2[3].x - w6) + fabsf(pr2[3].y - w7);
    return bf8_sum((t0 + t1) + (t2 + t3));
}

// exact path: f32 diffs (reference rounding) summed in f64; scalar LDS reads
__device__ __forceinline__ double sad_f64(const float* b, const float2* pr2) {
    double e0 = (double)fabsf(pr2[0].x - b[0]) + (double)fabsf(pr2[0].y - b[1]);
    double e1 = (double)fabsf(pr2[1].x - b[2]) + (double)fabsf(pr2[1].y - b[3]);
    double e2 = (double)fabsf(pr2[2].x - b[4]) + (double)fabsf(pr2[2].y - b[5]);
    double e3 = (double)fabsf(pr2[3].x - b[6]) + (double)fabsf(pr2[3].y - b[7]);
    return bf8_sumd((e0 + e1) + (e2 + e3));
}

__global__ void __launch_bounds__(256)
motion_pred_kernel(const float* __restrict__ x, float* __restrict__ out) {
    __shared__ float win[WSIZE];   // single copy, odd stride, 17,680 B

    int cta = blockIdx.x;
    int jb0 = (cta & 7) * 64;          // first pixel col of this CTA's blocks
    int bi0 = ((cta >> 3) & 15) * 4;   // first block row (4 per CTA)
    int bf  = cta >> 7;                // 0 .. NV*NF-1
    int f   = bf % NF;
    int b   = bf / NF;

    const float* imgP = x + (size_t)(b * TT + f + 1) * FRAME;  // current
    const float* imgI = x + (size_t)(b * TT + f)     * FRAME;  // reference

    int wy0 = bi0 * 8 - 8;   // window origin
    int wx0 = jb0 - 8;

    // ---- target-copy prefetch: ISSUE loads first, so their HBM latency
    //      shares the staging loads' latency window (async-STAGE split).
    //      Values stay in registers through the search; stores at CTA end. ----
    float c0v0 = 0.f, c0v1 = 0.f, c0v2 = 0.f, c0v3 = 0.f;
    float c1v0 = 0.f, c1v1 = 0.f, c1v2 = 0.f, c1v3 = 0.f;
    int chi  = min((cta + 1) * SPAN, N4);
    int idx0 = cta * SPAN + (int)threadIdx.x;
    int idx1 = idx0 + 256;
    bool cv0 = idx0 < chi, cv1 = idx1 < chi;
    {
        if (cv0) {
            unsigned o = (unsigned)idx0 * 4;
            unsigned fidx = o / (CW * CW);
            unsigned rem  = o - fidx * (CW * CW);
            unsigned rr   = rem / CW;
            unsigned cc0  = rem - rr * CW;
            unsigned bb   = fidx / NF, fi = fidx - bb * NF;
            const float* src = x + (size_t)(bb * TT + fi + 2) * FRAME;
            unsigned c, rr2;
            c = cc0 + 0; rr2 = rr; if (c >= CW) { c -= CW; rr2 += 1; } c0v0 = src[(rr2 + CRP) * WW + c + CRP];
            c = cc0 + 1; rr2 = rr; if (c >= CW) { c -= CW; rr2 += 1; } c0v1 = src[(rr2 + CRP) * WW + c + CRP];
            c = cc0 + 2; rr2 = rr; if (c >= CW) { c -= CW; rr2 += 1; } c0v2 = src[(rr2 + CRP) * WW + c + CRP];
            c = cc0 + 3; rr2 = rr; if (c >= CW) { c -= CW; rr2 += 1; } c0v3 = src[(rr2 + CRP) * WW + c + CRP];
        }
        if (cv1) {
            unsigned o = (unsigned)idx1 * 4;
            unsigned fidx = o / (CW * CW);
            unsigned rem  = o - fidx * (CW * CW);
            unsigned rr   = rem / CW;
            unsigned cc0  = rem - rr * CW;
            unsigned bb   = fidx / NF, fi = fidx - bb * NF;
            const float* src = x + (size_t)(bb * TT + fi + 2) * FRAME;
            unsigned c, rr2;
            c = cc0 + 0; rr2 = rr; if (c >= CW) { c -= CW; rr2 += 1; } c1v0 = src[(rr2 + CRP) * WW + c + CRP];
            c = cc0 + 1; rr2 = rr; if (c >= CW) { c -= CW; rr2 += 1; } c1v1 = src[(rr2 + CRP) * WW + c + CRP];
            c = cc0 + 2; rr2 = rr; if (c >= CW) { c -= CW; rr2 += 1; } c1v2 = src[(rr2 + CRP) * WW + c + CRP];
            c = cc0 + 3; rr2 = rr; if (c >= CW) { c -= CW; rr2 += 1; } c1v3 = src[(rr2 + CRP) * WW + c + CRP];
        }
    }

    // ---- stage reference window (scalar LDS writes; odd stride breaks 16B align) ----
    #pragma unroll
    for (int t = 0; t < 4; ++t) {
        int idx = t * 256 + threadIdx.x;
        if (idx < WROWS * (WCOLS / 4)) {
            int row = idx / (WCOLS / 4);
            int c4  = idx - row * (WCOLS / 4);
            int yy  = wy0 + row;
            int xg  = wx0 + c4 * 4;
            if (yy >= 0 && yy < HH && xg >= 0 && xg <= WW - 4) {
                float4 v = *(const float4*)(imgI + (size_t)yy * WW + xg);
                float* d = win + WBASE + row * WSTR + c4 * 4;
                d[0] = v.x; d[1] = v.y; d[2] = v.z; d[3] = v.w;
            }
        }
    }
    __syncthreads();

    // pin the prefetched values here: forces the loads to have materialized
    // (wait overlaps the staging phase's own waits) and stops the scheduler
    // from sinking the loads down to the stores at the end.
    asm volatile("" : "+v"(c0v0), "+v"(c0v1), "+v"(c0v2), "+v"(c0v3),
                      "+v"(c1v0), "+v"(c1v1), "+v"(c1v2), "+v"(c1v3));

    int w    = threadIdx.x >> 6;   // wave in CTA → block row bi0+w
    int lane = threadIdx.x & 63;
    int g = lane >> 3;             // block within wave (0..7)
    int r = lane & 7;              // row within block

    int i  = (bi0 + w) * 8;
    int jg = jb0 + g * 8;

    // this lane's current-block row as float2 pairs
    float2 pr2[4];
    {
        const float4* prow = (const float4*)(imgP + (size_t)(i + r) * WW + jg);
        float4 p0 = prow[0], p1 = prow[1];
        pr2[0] = make_float2(p0.x, p0.y); pr2[1] = make_float2(p0.z, p0.w);
        pr2[2] = make_float2(p1.x, p1.y); pr2[3] = make_float2(p1.z, p1.w);
    }

    // per-block search bounds (valid y+d in [yLo,yHi], x+d in [xLo,xHi])
    int yLo = max(i - 8, 0),  yHi = min(i + 8, HH - 8);
    int xLo = max(jg - 8, 0), xHi = min(jg + 8, WW - 8);

    int y = i, xx = jg;
    int ctr;                       // dword index of (y, xx) pixel in win
    bool vy[5], vx[5];

    auto precomp = [&]() {
        ctr = WBASE + (y - wy0 + r) * WSTR + (xx - wx0);
        #pragma unroll
        for (int d = -2; d <= 2; ++d) {
            vy[d + 2] = (y + d >= yLo) && (y + d <= yHi);
            vx[d + 2] = (xx + d >= xLo) && (xx + d <= xHi);
        }
    };
    auto evalqd = [&](int dy, int dx) -> double {
        const float* bp = win + (ctr + dy * WSTR + dx);
        double s = sad_f64(bp, pr2);
        return (vy[dy + 2] && vx[dx + 2]) ? s : 1e30;
    };

    // LDSP tables (dx,dy), index order = reference candidate order
    const int LDx[9] = {0,-1, 1,-2, 0, 2,-1, 1, 0};
    const int LDy[9] = {-2,-1,-1, 0, 0, 0, 1, 1, 2};

    precomp();
    float cc;
    {
        const float* pc = win + ctr;
        float c0 = pc[0], c1 = pc[1], c2 = pc[2], c3 = pc[3];
        float c4 = pc[4], c5 = pc[5], c6 = pc[6], c7 = pc[7];
        cc = sad8(c0, c1, c2, c3, c4, c5, c6, c7, pr2);   // center (always valid)
    }
    bool done = (cc == 0.0f);          // f32 sum of non-negatives == 0 iff exact 0
    int k = 0;

    while (__any((!done) && (k < 16))) {
        bool active = (!done) && (k < 16);
        if (active) {                  // exec-mask done groups: no LDS traffic from them
            precomp();

            // ---- batched union row loads ----
            const float* pm2 = win + (ctr - 2 * WSTR);
            const float* pm1 = win + (ctr - WSTR - 1);
            const float* pz  = win + (ctr - 2);
            const float* pp1 = win + (ctr + WSTR - 1);
            const float* pp2 = win + (ctr + 2 * WSTR);
            float a2[8], a1v[10], a0v[12], b1v[10], b2[8];
            #pragma unroll
            for (int t = 0; t < 8; ++t)  a2[t]  = pm2[t];
            #pragma unroll
            for (int t = 0; t < 10; ++t) a1v[t] = pm1[t];
            #pragma unroll
            for (int t = 0; t < 12; ++t) a0v[t] = pz[t];
            #pragma unroll
            for (int t = 0; t < 10; ++t) b1v[t] = pp1[t];
            #pragma unroll
            for (int t = 0; t < 8; ++t)  b2[t]  = pp2[t];

            float s0 = sad8(a2[0],  a2[1],  a2[2],  a2[3],  a2[4],  a2[5],  a2[6],  a2[7],  pr2); // (-2, 0)
            float s1 = sad8(a1v[0], a1v[1], a1v[2], a1v[3], a1v[4], a1v[5], a1v[6], a1v[7], pr2); // (-1,-1)
            float s2 = sad8(a1v[2], a1v[3], a1v[4], a1v[5], a1v[6], a1v[7], a1v[8], a1v[9], pr2); // (-1,+1)
            float s3 = sad8(a0v[0], a0v[1], a0v[2], a0v[3], a0v[4], a0v[5], a0v[6], a0v[7], pr2); // ( 0,-2)
            float s5 = sad8(a0v[4], a0v[5], a0v[6], a0v[7], a0v[8], a0v[9], a0v[10],a0v[11],pr2); // ( 0,+2)
            float s6 = sad8(b1v[0], b1v[1], b1v[2], b1v[3], b1v[4], b1v[5], b1v[6], b1v[7], pr2); // (+1,-1)
            float s7 = sad8(b1v[2], b1v[3], b1v[4], b1v[5], b1v[6], b1v[7], b1v[8], b1v[9], pr2); // (+1,+1)
            float s8 = sad8(b2[0],  b2[1],  b2[2],  b2[3],  b2[4],  b2[5],  b2[6],  b2[7],  pr2); // (+2, 0)

            float cf[9];
            cf[0] = (vy[0] && vx[2]) ? s0 : 1e30f;
            cf[1] = (vy[1] && vx[1]) ? s1 : 1e30f;
            cf[2] = (vy[1] && vx[3]) ? s2 : 1e30f;
            cf[3] = (vy[2] && vx[0]) ? s3 : 1e30f;
            cf[4] = cc;
            cf[5] = (vy[2] && vx[4]) ? s5 : 1e30f;
            cf[6] = (vy[3] && vx[1]) ? s6 : 1e30f;
            cf[7] = (vy[3] && vx[3]) ? s7 : 1e30f;
            cf[8] = (vy[4] && vx[2]) ? s8 : 1e30f;

            float m1 = 1e38f, m2 = 1e38f; int b1 = 0;
            #pragma unroll
            for (int q = 0; q < 9; ++q) {
                float cq = cf[q];
                bool lt = cq < m1;            // strict '<' => first-min (jnp.argmin)
                m2 = lt ? m1 : fminf(m2, cq);
                m1 = lt ? cq : m1;
                b1 = lt ? q  : b1;
            }
            bool needx = (m2 - m1) < TH;      // group-uniform
            if (__any(needx)) {               // vote among ACTIVE lanes only
                if (needx) {                  // only needx groups pay the f64 path
                    double e1 = 1e300; int eb = 0;
                    #pragma unroll
                    for (int q = 0; q < 9; ++q) {
                        double eq = evalqd(LDy[q], LDx[q]);
                        bool lt = eq < e1;
                        e1 = lt ? eq : e1; eb = lt ? q : eb;
                    }
                    float mf = cf[0];
                    #pragma unroll
                    for (int q = 1; q < 9; ++q) mf = (eb == q) ? cf[q] : mf;
                    b1 = eb; m1 = mf;
                }
            }
            int dy = (b1 == 0) ? -2 : (b1 == 1 || b1 == 2) ? -1
                   : (b1 == 6 || b1 == 7) ? 1 : (b1 == 8) ? 2 : 0;
            int dx = (b1 == 1 || b1 == 6) ? -1 : (b1 == 2 || b1 == 7) ? 1
                   : (b1 == 3) ? -2 : (b1 == 5) ? 2 : 0;
            y += dy; xx += dx;
            cc = m1;
            done = (b1 == 4);
            k++;
        }
    }

    // SDSP refinement (center at q=2, carried cc)
    {
        precomp();
        const int SDx[5] = {0,-1, 0, 1, 0};
        const int SDy[5] = {-1, 0, 0, 0, 1};

        const float* qm1 = win + (ctr - WSTR);
        const float* qz  = win + (ctr - 1);
        const float* qp1 = win + (ctr + WSTR);
        float u0[8], u1[10], u2[8];
        #pragma unroll
        for (int t = 0; t < 8; ++t)  u0[t] = qm1[t];
        #pragma unroll
        for (int t = 0; t < 10; ++t) u1[t] = qz[t];
        #pragma unroll
        for (int t = 0; t < 8; ++t)  u2[t] = qp1[t];

        float t0 = sad8(u0[0], u0[1], u0[2], u0[3], u0[4], u0[5], u0[6], u0[7], pr2); // (-1, 0)
        float t1 = sad8(u1[0], u1[1], u1[2], u1[3], u1[4], u1[5], u1[6], u1[7], pr2); // ( 0,-1)
        float t3 = sad8(u1[2], u1[3], u1[4], u1[5], u1[6], u1[7], u1[8], u1[9], pr2); // ( 0,+1)
        float t4 = sad8(u2[0], u2[1], u2[2], u2[3], u2[4], u2[5], u2[6], u2[7], pr2); // (+1, 0)

        float cf5[5];
        cf5[0] = (vy[1] && vx[2]) ? t0 : 1e30f;
        cf5[1] = (vy[2] && vx[1]) ? t1 : 1e30f;
        cf5[2] = cc;
        cf5[3] = (vy[2] && vx[3]) ? t3 : 1e30f;
        cf5[4] = (vy[3] && vx[2]) ? t4 : 1e30f;

        float m1 = 1e38f, m2 = 1e38f; int sb = 0;
        #pragma unroll
        for (int q = 0; q < 5; ++q) {
            float cq = cf5[q];
            bool lt = cq < m1;
            m2 = lt ? m1 : fminf(m2, cq);
            m1 = lt ? cq : m1;
            sb = lt ? q  : sb;
        }
        bool needx = (m2 - m1) < TH;
        if (__any(needx)) {
            if (needx) {
                double e1 = 1e300; int eb = 0;
                #pragma unroll
                for (int q = 0; q < 5; ++q) {
                    double eq = evalqd(SDy[q], SDx[q]);
                    bool lt = eq < e1;
                    e1 = lt ? eq : e1; eb = lt ? q : eb;
                }
                sb = eb;
            }
        }
        y  += (sb == 0) ? -1 : (sb == 4) ? 1 : 0;
        xx += (sb == 1) ? -1 : (sb == 3) ? 1 : 0;
    }

    int dy = y - i, dx = xx - jg;

    // write this lane's warped row (pred), cropped
    int gy = i + r;
    if (gy >= CRP && gy < HH - CRP) {
        const float* src = imgP + (size_t)(i + dy + r) * WW + (jg + dx);
        size_t obase = TGT_SIZE
            + (((size_t)(b * NF + f)) * CW + (size_t)(gy - CRP)) * CW - CRP;
        #pragma unroll
        for (int c = 0; c < 8; ++c) {
            int gx = jg + c;
            if (gx >= CRP && gx < WW - CRP)
                out[obase + gx] = src[c];
        }
    }

    // ---- target-copy stores: values already in registers (fire-and-forget) ----
    if (cv0) {
        float4 v = make_float4(c0v0, c0v1, c0v2, c0v3);
        *(float4*)(out + (size_t)idx0 * 4) = v;
    }
    if (cv1) {
        float4 v = make_float4(c1v0, c1v1, c1v2, c1v3);
        *(float4*)(out + (size_t)idx1 * 4) = v;
    }
}

extern "C" void kernel_launch(void* const* d_in, const int* in_sizes, int n_in,
                              void* d_out, int out_size, void* d_ws, size_t ws_size,
                              hipStream_t stream) {
    const float* x = (const float*)d_in[0];
    float* out = (float*)d_out;

    // single dispatch: prefetched target copy + motion search + pred write
    motion_pred_kernel<<<NMOTION, 256, 0, stream>>>(x, out);
}

// Round 9
// 209.690 us; speedup vs baseline: 1.0610x; 1.0610x over previous
//
#include <hip/hip_runtime.h>

#define HH 512
#define WW 512
#define TT 16
#define NF 14   // pred/target frames per video
#define NV 4    // videos
#define CRP 17
#define CW 478  // cropped width
#define TGT_SIZE ((size_t)NV * NF * CW * CW)   // 12,795,104
#define FRAME ((size_t)HH * WW)

#define WROWS 48
#define WCOLS 80
#define WSTR  85                 // ODD stride: 85 % 32 = 21 -> per-group row spread
                                 // covers all residues mod 8 (bank-conflict fix)
#define WBASE (2 * WSTR + 2)     // 2-row/2-col margin so all batched reads are in-bounds
#define WSIZE ((WROWS + 4) * WSTR)   // 52*85 = 4420 dwords = 17,680 B
#define TH    1e-3f              // hybrid fallback margin (bound on f32 tree err ~7e-5)

#define NMOTION (NV * NF * 16 * 8)           // 7168 motion CTAs

// ---- 8-lane group sum entirely on the VALU ----
// Bitwise-identical to __shfl_xor(1)/(2)/(4):
//   quad_perm [1,0,3,2] == lane^1 ; quad_perm [2,3,0,1] == lane^2 ;
//   row_half_mirror == lane^4 once the value is quad-uniform.
template <int CTRL>
__device__ __forceinline__ float dpp_add(float v) {
    int x = __builtin_amdgcn_update_dpp(0, __float_as_int(v), CTRL, 0xF, 0xF, true);
    return v + __int_as_float(x);
}
__device__ __forceinline__ float bf8_sum(float v) {
    v = dpp_add<0xB1>(v);    // quad_perm [1,0,3,2]
    v = dpp_add<0x4E>(v);    // quad_perm [2,3,0,1]
    v = dpp_add<0x141>(v);   // row_half_mirror
    return v;
}
__device__ __forceinline__ double bf8_sumd(double v) {   // rare exact path
    v += __shfl_xor(v, 1, 64);
    v += __shfl_xor(v, 2, 64);
    v += __shfl_xor(v, 4, 64);
    return v;
}

// f32 SAD of this lane's 8-pixel row vs 8 window scalars already in registers,
// then 3-stage group reduce. Term order/association identical to the original.
__device__ __forceinline__ float sad8(float w0, float w1, float w2, float w3,
                                      float w4, float w5, float w6, float w7,
                                      const float2* pr2) {
    float t0 = fabsf(pr2[0].x - w0) + fabsf(pr2[0].y - w1);
    float t1 = fabsf(pr2[1].x - w2) + fabsf(pr2[1].y - w3);
    float t2 = fabsf(pr2[2].x - w4) + fabsf(pr2[2].y - w5);
    float t3 = fabsf(pr2[3].x - w6) + fabsf(pr2[3].y - w7);
    return bf8_sum((t0 + t1) + (t2 + t3));
}

// exact path: f32 diffs (reference rounding) summed in f64; scalar LDS reads
__device__ __forceinline__ double sad_f64(const float* b, const float2* pr2) {
    double e0 = (double)fabsf(pr2[0].x - b[0]) + (double)fabsf(pr2[0].y - b[1]);
    double e1 = (double)fabsf(pr2[1].x - b[2]) + (double)fabsf(pr2[1].y - b[3]);
    double e2 = (double)fabsf(pr2[2].x - b[4]) + (double)fabsf(pr2[2].y - b[5]);
    double e3 = (double)fabsf(pr2[3].x - b[6]) + (double)fabsf(pr2[3].y - b[7]);
    return bf8_sumd((e0 + e1) + (e2 + e3));
}

__global__ void __launch_bounds__(256)
motion_pred_kernel(const float* __restrict__ x, float* __restrict__ out) {
    __shared__ float win[WSIZE];   // single copy, odd stride, 17,680 B

    int cta = blockIdx.x;
    int jb0 = (cta & 7) * 64;          // first pixel col of this CTA's blocks
    int bi0 = ((cta >> 3) & 15) * 4;   // first block row (4 per CTA)
    int bf  = cta >> 7;                // 0 .. NV*NF-1
    int f   = bf % NF;
    int b   = bf / NF;

    const float* imgP = x + (size_t)(b * TT + f + 1) * FRAME;  // current
    const float* imgI = x + (size_t)(b * TT + f)     * FRAME;  // reference

    int wy0 = bi0 * 8 - 8;   // window origin
    int wx0 = jb0 - 8;

    int w    = threadIdx.x >> 6;   // wave in CTA → block row bi0+w
    int lane = threadIdx.x & 63;
    int g = lane >> 3;             // block within wave (0..7)
    int r = lane & 7;              // row within block

    int i  = (bi0 + w) * 8;
    int jg = jb0 + g * 8;

    // ---- target-copy prefetch: row-mapped, divide-free addressing.
    //      cta&127 spans 128 positions per frame; 4 rows/CTA, one row/wave.
    //      Loads clamped in-bounds (redundant reads benign); stores masked. ----
    int tr   = (cta & 127) * 4 + w;            // target row (0..511)
    bool trv = (tr < CW);                      // wave-uniform store mask
    int trc  = min(tr, CW - 1);
    int tc0  = min(lane * 8, CW - 8);          // 8 in-bounds cols (overlap = same data)
    float cv[8];
    {
        const float* csrc = x + (size_t)(b * TT + f + 2) * FRAME
                              + (size_t)(trc + CRP) * WW + CRP + tc0;
        #pragma unroll
        for (int e = 0; e < 8; ++e) cv[e] = csrc[e];
    }

    // ---- pred-row prefetch (issued before staging so latency shares the drain) ----
    float2 pr2[4];
    {
        const float4* prow = (const float4*)(imgP + (size_t)(i + r) * WW + jg);
        float4 p0 = prow[0], p1 = prow[1];
        pr2[0] = make_float2(p0.x, p0.y); pr2[1] = make_float2(p0.z, p0.w);
        pr2[2] = make_float2(p1.x, p1.y); pr2[3] = make_float2(p1.z, p1.w);
    }

    // ---- stage reference window (scalar LDS writes; odd stride breaks 16B align) ----
    #pragma unroll
    for (int t = 0; t < 4; ++t) {
        int idx = t * 256 + threadIdx.x;
        if (idx < WROWS * (WCOLS / 4)) {
            int row = idx / (WCOLS / 4);
            int c4  = idx - row * (WCOLS / 4);
            int yy  = wy0 + row;
            int xg  = wx0 + c4 * 4;
            if (yy >= 0 && yy < HH && xg >= 0 && xg <= WW - 4) {
                float4 v = *(const float4*)(imgI + (size_t)yy * WW + xg);
                float* d = win + WBASE + row * WSTR + c4 * 4;
                d[0] = v.x; d[1] = v.y; d[2] = v.z; d[3] = v.w;
            }
        }
    }
    __syncthreads();

    // pin prefetched values: loads materialize under the barrier drain and the
    // scheduler can't sink them down to their uses.
    asm volatile("" : "+v"(cv[0]), "+v"(cv[1]), "+v"(cv[2]), "+v"(cv[3]),
                      "+v"(cv[4]), "+v"(cv[5]), "+v"(cv[6]), "+v"(cv[7]),
                      "+v"(pr2[0].x), "+v"(pr2[0].y), "+v"(pr2[1].x), "+v"(pr2[1].y),
                      "+v"(pr2[2].x), "+v"(pr2[2].y), "+v"(pr2[3].x), "+v"(pr2[3].y));

    // per-block search bounds (valid y+d in [yLo,yHi], x+d in [xLo,xHi])
    int yLo = max(i - 8, 0),  yHi = min(i + 8, HH - 8);
    int xLo = max(jg - 8, 0), xHi = min(jg + 8, WW - 8);

    int y = i, xx = jg;
    int ctr;                       // dword index of (y, xx) pixel in win
    bool vy[5], vx[5];

    auto precomp = [&]() {
        ctr = WBASE + (y - wy0 + r) * WSTR + (xx - wx0);
        #pragma unroll
        for (int d = -2; d <= 2; ++d) {
            vy[d + 2] = (y + d >= yLo) && (y + d <= yHi);
            vx[d + 2] = (xx + d >= xLo) && (xx + d <= xHi);
        }
    };
    auto evalqd = [&](int dy, int dx) -> double {
        const float* bp = win + (ctr + dy * WSTR + dx);
        double s = sad_f64(bp, pr2);
        return (vy[dy + 2] && vx[dx + 2]) ? s : 1e30;
    };

    // LDSP tables (dx,dy), index order = reference candidate order
    const int LDx[9] = {0,-1, 1,-2, 0, 2,-1, 1, 0};
    const int LDy[9] = {-2,-1,-1, 0, 0, 0, 1, 1, 2};

    precomp();
    float cc;
    {
        const float* pc = win + ctr;
        float c0 = pc[0], c1 = pc[1], c2 = pc[2], c3 = pc[3];
        float c4 = pc[4], c5 = pc[5], c6 = pc[6], c7 = pc[7];
        cc = sad8(c0, c1, c2, c3, c4, c5, c6, c7, pr2);   // center (always valid)
    }
    bool done = (cc == 0.0f);          // f32 sum of non-negatives == 0 iff exact 0
    int k = 0;

    while (__any((!done) && (k < 16))) {
        bool active = (!done) && (k < 16);
        if (active) {                  // exec-mask done groups: no LDS traffic from them
            precomp();

            // ---- batched union row loads ----
            const float* pm2 = win + (ctr - 2 * WSTR);
            const float* pm1 = win + (ctr - WSTR - 1);
            const float* pz  = win + (ctr - 2);
            const float* pp1 = win + (ctr + WSTR - 1);
            const float* pp2 = win + (ctr + 2 * WSTR);
            float a2[8], a1v[10], a0v[12], b1v[10], b2[8];
            #pragma unroll
            for (int t = 0; t < 8; ++t)  a2[t]  = pm2[t];
            #pragma unroll
            for (int t = 0; t < 10; ++t) a1v[t] = pm1[t];
            #pragma unroll
            for (int t = 0; t < 12; ++t) a0v[t] = pz[t];
            #pragma unroll
            for (int t = 0; t < 10; ++t) b1v[t] = pp1[t];
            #pragma unroll
            for (int t = 0; t < 8; ++t)  b2[t]  = pp2[t];

            float s0 = sad8(a2[0],  a2[1],  a2[2],  a2[3],  a2[4],  a2[5],  a2[6],  a2[7],  pr2); // (-2, 0)
            float s1 = sad8(a1v[0], a1v[1], a1v[2], a1v[3], a1v[4], a1v[5], a1v[6], a1v[7], pr2); // (-1,-1)
            float s2 = sad8(a1v[2], a1v[3], a1v[4], a1v[5], a1v[6], a1v[7], a1v[8], a1v[9], pr2); // (-1,+1)
            float s3 = sad8(a0v[0], a0v[1], a0v[2], a0v[3], a0v[4], a0v[5], a0v[6], a0v[7], pr2); // ( 0,-2)
            float s5 = sad8(a0v[4], a0v[5], a0v[6], a0v[7], a0v[8], a0v[9], a0v[10],a0v[11],pr2); // ( 0,+2)
            float s6 = sad8(b1v[0], b1v[1], b1v[2], b1v[3], b1v[4], b1v[5], b1v[6], b1v[7], pr2); // (+1,-1)
            float s7 = sad8(b1v[2], b1v[3], b1v[4], b1v[5], b1v[6], b1v[7], b1v[8], b1v[9], pr2); // (+1,+1)
            float s8 = sad8(b2[0],  b2[1],  b2[2],  b2[3],  b2[4],  b2[5],  b2[6],  b2[7],  pr2); // (+2, 0)

            float cf[9];
            cf[0] = (vy[0] && vx[2]) ? s0 : 1e30f;
            cf[1] = (vy[1] && vx[1]) ? s1 : 1e30f;
            cf[2] = (vy[1] && vx[3]) ? s2 : 1e30f;
            cf[3] = (vy[2] && vx[0]) ? s3 : 1e30f;
            cf[4] = cc;
            cf[5] = (vy[2] && vx[4]) ? s5 : 1e30f;
            cf[6] = (vy[3] && vx[1]) ? s6 : 1e30f;
            cf[7] = (vy[3] && vx[3]) ? s7 : 1e30f;
            cf[8] = (vy[4] && vx[2]) ? s8 : 1e30f;

            float m1 = 1e38f, m2 = 1e38f; int b1 = 0;
            #pragma unroll
            for (int q = 0; q < 9; ++q) {
                float cq = cf[q];
                bool lt = cq < m1;            // strict '<' => first-min (jnp.argmin)
                m2 = lt ? m1 : fminf(m2, cq);
                m1 = lt ? cq : m1;
                b1 = lt ? q  : b1;
            }
            bool needx = (m2 - m1) < TH;      // group-uniform
            if (__any(needx)) {               // vote among ACTIVE lanes only
                if (needx) {                  // only needx groups pay the f64 path
                    double e1 = 1e300; int eb = 0;
                    #pragma unroll
                    for (int q = 0; q < 9; ++q) {
                        double eq = evalqd(LDy[q], LDx[q]);
                        bool lt = eq < e1;
                        e1 = lt ? eq : e1; eb = lt ? q : eb;
                    }
                    float mf = cf[0];
                    #pragma unroll
                    for (int q = 1; q < 9; ++q) mf = (eb == q) ? cf[q] : mf;
                    b1 = eb; m1 = mf;
                }
            }
            int dy = (b1 == 0) ? -2 : (b1 == 1 || b1 == 2) ? -1
                   : (b1 == 6 || b1 == 7) ? 1 : (b1 == 8) ? 2 : 0;
            int dx = (b1 == 1 || b1 == 6) ? -1 : (b1 == 2 || b1 == 7) ? 1
                   : (b1 == 3) ? -2 : (b1 == 5) ? 2 : 0;
            y += dy; xx += dx;
            cc = m1;
            done = (b1 == 4);
            k++;
        }
    }

    // SDSP refinement (center at q=2, carried cc)
    {
        precomp();
        const int SDx[5] = {0,-1, 0, 1, 0};
        const int SDy[5] = {-1, 0, 0, 0, 1};

        const float* qm1 = win + (ctr - WSTR);
        const float* qz  = win + (ctr - 1);
        const float* qp1 = win + (ctr + WSTR);
        float u0[8], u1[10], u2[8];
        #pragma unroll
        for (int t = 0; t < 8; ++t)  u0[t] = qm1[t];
        #pragma unroll
        for (int t = 0; t < 10; ++t) u1[t] = qz[t];
        #pragma unroll
        for (int t = 0; t < 8; ++t)  u2[t] = qp1[t];

        float t0 = sad8(u0[0], u0[1], u0[2], u0[3], u0[4], u0[5], u0[6], u0[7], pr2); // (-1, 0)
        float t1 = sad8(u1[0], u1[1], u1[2], u1[3], u1[4], u1[5], u1[6], u1[7], pr2); // ( 0,-1)
        float t3 = sad8(u1[2], u1[3], u1[4], u1[5], u1[6], u1[7], u1[8], u1[9], pr2); // ( 0,+1)
        float t4 = sad8(u2[0], u2[1], u2[2], u2[3], u2[4], u2[5], u2[6], u2[7], pr2); // (+1, 0)

        float cf5[5];
        cf5[0] = (vy[1] && vx[2]) ? t0 : 1e30f;
        cf5[1] = (vy[2] && vx[1]) ? t1 : 1e30f;
        cf5[2] = cc;
        cf5[3] = (vy[2] && vx[3]) ? t3 : 1e30f;
        cf5[4] = (vy[3] && vx[2]) ? t4 : 1e30f;

        float m1 = 1e38f, m2 = 1e38f; int sb = 0;
        #pragma unroll
        for (int q = 0; q < 5; ++q) {
            float cq = cf5[q];
            bool lt = cq < m1;
            m2 = lt ? m1 : fminf(m2, cq);
            m1 = lt ? cq : m1;
            sb = lt ? q  : sb;
        }
        bool needx = (m2 - m1) < TH;
        if (__any(needx)) {
            if (needx) {
                double e1 = 1e300; int eb = 0;
                #pragma unroll
                for (int q = 0; q < 5; ++q) {
                    double eq = evalqd(SDy[q], SDx[q]);
                    bool lt = eq < e1;
                    e1 = lt ? eq : e1; eb = lt ? q : eb;
                }
                sb = eb;
            }
        }
        y  += (sb == 0) ? -1 : (sb == 4) ? 1 : 0;
        xx += (sb == 1) ? -1 : (sb == 3) ? 1 : 0;
    }

    int dy = y - i, dx = xx - jg;

    // write this lane's warped row (pred), cropped
    int gy = i + r;
    if (gy >= CRP && gy < HH - CRP) {
        const float* src = imgP + (size_t)(i + dy + r) * WW + (jg + dx);
        size_t obase = TGT_SIZE
            + (((size_t)(b * NF + f)) * CW + (size_t)(gy - CRP)) * CW - CRP;
        #pragma unroll
        for (int c = 0; c < 8; ++c) {
            int gx = jg + c;
            if (gx >= CRP && gx < WW - CRP)
                out[obase + gx] = src[c];
        }
    }

    // ---- target-copy stores: values already in registers; 8B-aligned float2.
    //      (bf*CW^2 + tr*CW + tc0 is always even.) Wave-uniform mask. ----
    if (trv) {
        float* ob = out + (size_t)bf * (CW * CW) + (size_t)tr * CW + tc0;
        *(float2*)(ob + 0) = make_float2(cv[0], cv[1]);
        *(float2*)(ob + 2) = make_float2(cv[2], cv[3]);
        *(float2*)(ob + 4) = make_float2(cv[4], cv[5]);
        *(float2*)(ob + 6) = make_float2(cv[6], cv[7]);
    }
}

extern "C" void kernel_launch(void* const* d_in, const int* in_sizes, int n_in,
                              void* d_out, int out_size, void* d_ws, size_t ws_size,
                              hipStream_t stream) {
    const float* x = (const float*)d_in[0];
    float* out = (float*)d_out;

    // single dispatch: prefetched target copy + motion search + pred write
    motion_pred_kernel<<<NMOTION, 256, 0, stream>>>(x, out);
}